// Round 14
// baseline (598.220 us; speedup 1.0000x reference)
//
#include <hip/hip_runtime.h>
#include <stdint.h>

// K-means cluster aggregator, round 14: counted-vmcnt deep pipeline (T3+T4) on the
// round-13 async-staging structure. 4x8KB center dbuf, prefetch distance 3,
// s_waitcnt vmcnt(6) + raw s_barrier (never drain to 0 mid-loop), 48-node tile
// (LDS exactly 80 KB -> 2 blocks/CU). Dummy tail stages keep vmcnt counts uniform.
// Score chains bit-identical to the proven rounds-2/3/4/7/8/13 path -> absmax 8.0.

typedef _Float16 f16x8  __attribute__((ext_vector_type(8)));
typedef float    f32x4  __attribute__((ext_vector_type(4)));

#define DD 512   // feature dim (fixed)
#define KK 1024  // clusters (fixed)
#define NT 48    // node tile (48 KB LDS)

static __device__ __forceinline__ unsigned orderable(float s) {
    unsigned u = __float_as_uint(s);
    return (u & 0x80000000u) ? ~u : (u | 0x80000000u);
}

static __device__ __forceinline__ void gload_lds16(const void* gsrc, void* ldst) {
    __builtin_amdgcn_global_load_lds(
        (const __attribute__((address_space(1))) unsigned int*)gsrc,
        (__attribute__((address_space(3))) unsigned int*)ldst, 16, 0, 0);
}

// ---- kernel 0a/0b: canonical representative per duplicate-center group ------------
__global__ void canon_first(const int* __restrict__ center_ind,
                            unsigned* __restrict__ firstk, int K) {
    int k = (int)(blockIdx.x * blockDim.x + threadIdx.x);
    if (k < K) atomicMin(&firstk[center_ind[k]], (unsigned)k);
}
__global__ void canon_map(const int* __restrict__ center_ind,
                          const unsigned* __restrict__ firstk,
                          unsigned* __restrict__ canon, int K) {
    int k = (int)(blockIdx.x * blockDim.x + threadIdx.x);
    if (k < K) canon[k] = firstk[center_ind[k]];
}

// ---- kernel 1: gather centers -> 16x16x32 A-fragment layout + fp32 ||c||^2 --------
// Fragment layout (f16 elems): center c -> tile t=c>>4, row r=c&15; 8-dim chunk j:
//   offset = ((t*64 + j)*16 + r) * 8        (per tile: 8192 f16 = 16 KB)
// Per (t, 32-dim step s): bytes [t*16384 + s*1024, +1024) are one contiguous 1 KB
// block, lane l owns [l*16, l*16+16) — exactly global_load_lds's dst pattern.
__global__ void gather_centers(const float* __restrict__ nodes,
                               const int* __restrict__ center_ind,
                               _Float16* __restrict__ centf,    // [K*DD] fragmented
                               float* __restrict__ cent_sq,     // [K]
                               int K) {
    int k    = (int)blockIdx.x;
    int lane = (int)threadIdx.x;                 // 64 lanes; lane = chunk j
    int ci   = center_ind[k];
    const f32x4* p = reinterpret_cast<const f32x4*>(nodes + (size_t)ci * DD + lane * 8);
    f32x4 v0 = p[0], v1 = p[1];
    f16x8 h;
    h[0]=(_Float16)v0[0]; h[1]=(_Float16)v0[1]; h[2]=(_Float16)v0[2]; h[3]=(_Float16)v0[3];
    h[4]=(_Float16)v1[0]; h[5]=(_Float16)v1[1]; h[6]=(_Float16)v1[2]; h[7]=(_Float16)v1[3];
    int t = k >> 4, r = k & 15;
    *reinterpret_cast<f16x8*>(centf + ((size_t)((t * 64 + lane) * 16 + r) << 3)) = h;
    float ssq = v0[0]*v0[0]+v0[1]*v0[1]+v0[2]*v0[2]+v0[3]*v0[3]
              + v1[0]*v1[0]+v1[1]*v1[1]+v1[2]*v1[2]+v1[3]*v1[3];
    #pragma unroll
    for (int off = 32; off > 0; off >>= 1) ssq += __shfl_xor(ssq, off, 64);
    if (lane == 0) cent_sq[k] = ssq;
}

// ---- kernel 2: MFMA assign (counted-vmcnt center stream) --------------------------
// block: 48 nodes, 4 waves (256 thr); 128 d-steps over 8 center-tiles of 128.
// Per step: STAGE(gs+3) -> vmcnt(6) -> bar -> reads+MFMA -> bar. acc[2][3]=24 regs.
__launch_bounds__(256, 2)
__global__ void assign_mfma(const float* __restrict__ nodes,
                            const _Float16* __restrict__ centf,   // fragmented A
                            const float* __restrict__ cent_sq,    // [K]
                            unsigned long long* __restrict__ bestg, // [N], pre-0xFF
                            int N, int K) {
    __shared__ __align__(16) _Float16 nt[NT * DD];     // 48 KB, XOR-swizzled
    __shared__ __align__(16) _Float16 ab[4][4096];     // 4 x 8 KB center stream ring

    const int tid = (int)threadIdx.x;
    const int n0  = (int)blockIdx.x * NT;
    const int lane = tid & 63;
    const int wid  = tid >> 6;           // 0..3

    // stage node tile -> f16 LDS (proven layout): 48 rows x 64 chunks = 12 iters.
    #pragma unroll
    for (int it = 0; it < 12; ++it) {
        int f   = it * 256 + tid;
        int row = f >> 6;
        int d0  = (f & 63) << 3;
        f32x4 v0 = {0.f,0.f,0.f,0.f}, v1 = {0.f,0.f,0.f,0.f};
        if (n0 + row < N) {
            const f32x4* p = reinterpret_cast<const f32x4*>(nodes + (size_t)(n0 + row) * DD + d0);
            v0 = p[0]; v1 = p[1];
        }
        f16x8 h;
        h[0]=(_Float16)v0[0]; h[1]=(_Float16)v0[1]; h[2]=(_Float16)v0[2]; h[3]=(_Float16)v0[3];
        h[4]=(_Float16)v1[0]; h[5]=(_Float16)v1[1]; h[6]=(_Float16)v1[2]; h[7]=(_Float16)v1[3];
        int byte = ((row << 10) + (d0 << 1)) ^ ((row & 7) << 4);
        *reinterpret_cast<f16x8*>(reinterpret_cast<char*>(nt) + byte) = h;
    }

    const int l15 = lane & 15;
    const int g   = lane >> 4;           // k-slice group (and C-row group)
    const int swz = (l15 & 7) << 4;
    char* ntb = reinterpret_cast<char*>(nt);
    const char* cfb = reinterpret_cast<const char*>(centf);

    int bbase[3];
    #pragma unroll
    for (int nG = 0; nG < 3; ++nG) bbase[nG] = (((nG * 16 + l15) << 10) + (g << 4));

    // async stage of global step gs_ into ring buffer buf_ (2 issues/thread;
    // chunk c = i*4+wid is wave-uniform -> LDS c*1KB + lane*16, the gload pattern).
    #define STAGE(buf_, gs_)                                                         \
        { const int ct_ = (gs_) >> 4, s_ = (gs_) & 15;                               \
          _Pragma("unroll")                                                          \
          for (int i_ = 0; i_ < 2; ++i_) {                                           \
              const int c_ = i_ * 4 + wid;                                           \
              gload_lds16(cfb + (size_t)(ct_ * 8 + c_) * 16384                       \
                              + (size_t)s_ * 1024 + lane * 16,                       \
                          reinterpret_cast<char*>(&ab[buf_][0]) + c_ * 1024);        \
          } }

    f32x4 acc[2][3];
    #pragma unroll
    for (int a = 0; a < 2; ++a)
        #pragma unroll
        for (int b = 0; b < 3; ++b) { f32x4 z = {0.f,0.f,0.f,0.f}; acc[a][b] = z; }
    unsigned long long pk[3] = {~0ULL, ~0ULL, ~0ULL};

    STAGE(0, 0); STAGE(1, 1); STAGE(2, 2);
    __syncthreads();                     // one full drain: node ds_writes + stages 0-2

    for (int ct = 0; ct < 8; ++ct) {
        #pragma unroll
        for (int s = 0; s < 16; ++s) {
            const int gs = ct * 16 + s;
            // prefetch distance 3; dummy stage past the end keeps vmcnt uniform.
            {
                const int nx  = gs + 3;
                const int gsx = (nx < 128) ? nx : 0;        // dummy -> dead buffer
                STAGE((s + 3) & 3, gsx);
            }
            asm volatile("s_waitcnt vmcnt(6)" ::: "memory");  // stage(gs) landed (mine)
            __builtin_amdgcn_s_barrier();                     // everyone's stage(gs)
            __builtin_amdgcn_sched_barrier(0);                // pin reads below barrier

            const char* abb = reinterpret_cast<const char*>(&ab[s & 3][0]);
            f16x8 Afr[2], Bfr[3];
            #pragma unroll
            for (int t = 0; t < 2; ++t)   // chunks 2w,2w+1: lane-contiguous 1KB
                Afr[t] = *reinterpret_cast<const f16x8*>(
                    abb + ((2 * wid + t) << 10) + (lane << 4));
            #pragma unroll
            for (int nG = 0; nG < 3; ++nG)
                Bfr[nG] = *reinterpret_cast<const f16x8*>(
                    ntb + ((bbase[nG] + (s << 6)) ^ swz));

            __builtin_amdgcn_s_setprio(1);
            #pragma unroll
            for (int t = 0; t < 2; ++t)
                #pragma unroll
                for (int nG = 0; nG < 3; ++nG)
                    acc[t][nG] = __builtin_amdgcn_mfma_f32_16x16x32_f16(
                        Afr[t], Bfr[nG], acc[t][nG], 0, 0, 0);
            __builtin_amdgcn_s_setprio(0);
            __builtin_amdgcn_sched_barrier(0);                // pin MFMA above barrier
            __builtin_amdgcn_s_barrier();                     // reads done before reuse
        }

        // epilogue for ct: score = csq - 2*dot; running packed min.
        // C/D map: col(node) = lane&15, row(center) = g*4 + q  [proven]
        #pragma unroll
        for (int tC = 0; tC < 2; ++tC) {
            const int cb = ct * 128 + wid * 32 + tC * 16 + g * 4;
            f32x4 cs = *reinterpret_cast<const f32x4*>(cent_sq + cb);
            #pragma unroll
            for (int nG = 0; nG < 3; ++nG) {
                #pragma unroll
                for (int q = 0; q < 4; ++q) {
                    float sc = fmaf(-2.f, acc[tC][nG][q], cs[q]);
                    unsigned long long v =
                        ((unsigned long long)orderable(sc) << 32) | (unsigned)(cb + q);
                    pk[nG] = v < pk[nG] ? v : pk[nG];
                }
            }
        }
        #pragma unroll
        for (int a = 0; a < 2; ++a)
            #pragma unroll
            for (int b = 0; b < 3; ++b) { f32x4 z = {0.f,0.f,0.f,0.f}; acc[a][b] = z; }
    }
    #undef STAGE

    // wave-level cross-g reduce (proven), then one global atomicMin per (wave,node)
    #pragma unroll
    for (int nG = 0; nG < 3; ++nG) {
        unsigned long long p = pk[nG], o;
        o = __shfl_xor(p, 16, 64); p = o < p ? o : p;
        o = __shfl_xor(p, 32, 64); p = o < p ? o : p;
        int n = n0 + nG * 16 + l15;
        if (lane < 16 && n < N) atomicMin(&bestg[n], p);
    }
}

// ---- kernel 2b: finalize assignment + histogram from bestg ------------------------
__global__ void finalize(const unsigned long long* __restrict__ bestg,
                         const unsigned* __restrict__ canon,
                         unsigned* __restrict__ assignment,
                         unsigned* __restrict__ counts, int N) {
    int i = (int)(blockIdx.x * blockDim.x + threadIdx.x);
    if (i < N) {
        unsigned k = canon[(unsigned)(bestg[i] & 0xffffffffu)];
        assignment[i] = k;
        atomicAdd(&counts[k], 1u);
    }
}

// ---- kernel 3: exclusive scan of counts -> cursor ---------------------------------
__global__ void scan_offsets(const unsigned* __restrict__ counts,
                             unsigned* __restrict__ cursor) {
    __shared__ unsigned s[KK];
    int t = (int)threadIdx.x;            // 1024
    unsigned c = counts[t];
    s[t] = c;
    __syncthreads();
    for (int off = 1; off < KK; off <<= 1) {
        unsigned v = (t >= off) ? s[t - off] : 0u;
        __syncthreads();
        s[t] += v;
        __syncthreads();
    }
    cursor[t] = s[t] - c;                // exclusive
}

// ---- kernel 4: scatter packed (k<<20 | node) keys into sorted slots ---------------
__global__ void scatter_idx(const unsigned* __restrict__ assignment,
                            unsigned* __restrict__ cursor,
                            unsigned* __restrict__ keys, int N) {
    int i = (int)(blockIdx.x * blockDim.x + threadIdx.x);
    if (i < N) {
        unsigned k = assignment[i];
        unsigned slot = atomicAdd(&cursor[k], 1u);
        keys[slot] = (k << 20) | (unsigned)i;   // N < 2^20, K < 2^10
    }
}

// ---- kernel 5: balanced segmented reduction over sorted slots ---------------------
#define CHUNK 32
__launch_bounds__(256, 4)
__global__ void aggregate3(const float* __restrict__ nodes,
                           const unsigned* __restrict__ keys,   // [N] packed
                           float* __restrict__ out, int N) {
    const int tid  = (int)threadIdx.x;
    const int wid  = tid >> 6;
    const int lane = tid & 63;
    const int base = ((int)blockIdx.x * 4 + wid) * CHUNK;
    if (base >= N) return;
    const int n    = min(CHUNK, N - base);

    int sI = base + (lane & 31);
    unsigned myk = (sI < N) ? keys[sI] : 0u;

    f32x4 a0 = {0.f,0.f,0.f,0.f}, a1 = {0.f,0.f,0.f,0.f};
    int curk = -1;
    auto flush = [&](void) {
        float* dst = out + ((size_t)curk << 9) + lane * 8;
        #pragma unroll
        for (int e = 0; e < 4; ++e) atomicAdd(dst + e, a0[e]);
        #pragma unroll
        for (int e = 0; e < 4; ++e) atomicAdd(dst + 4 + e, a1[e]);
    };

    int j = 0;
    while (j < n) {
        int b = n - j; if (b > 4) b = 4;
        f32x4 r[4][2];
        int   kk[4];
        #pragma unroll
        for (int t = 0; t < 4; ++t) {
            if (t < b) {
                unsigned key = __shfl(myk, j + t, 64);
                kk[t] = (int)(key >> 20);
                const f32x4* p = reinterpret_cast<const f32x4*>(
                    nodes + ((size_t)(key & 0xFFFFFu) << 9) + lane * 8);
                r[t][0] = p[0];
                r[t][1] = p[1];
            }
        }
        #pragma unroll
        for (int t = 0; t < 4; ++t) {
            if (t < b) {
                if (kk[t] != curk) {
                    if (curk >= 0) flush();
                    curk = kk[t];
                    f32x4 z = {0.f,0.f,0.f,0.f}; a0 = z; a1 = z;
                }
                a0 += r[t][0];
                a1 += r[t][1];
            }
        }
        j += 4;
    }
    if (curk >= 0) flush();
}

extern "C" void kernel_launch(void* const* d_in, const int* in_sizes, int n_in,
                              void* d_out, int out_size, void* d_ws, size_t ws_size,
                              hipStream_t stream) {
    const float* nodes      = (const float*)d_in[0];
    const int*   center_ind = (const int*)d_in[1];
    int K = in_sizes[1];                  // 1024
    int D = out_size / K;                 // 512 (DD)
    int N = in_sizes[0] / D;              // 100000

    char* ws = (char*)d_ws;
    _Float16* centf      = (_Float16*)ws;                          // K*DD*2 = 1 MB
    size_t    o          = (size_t)K * DD * 2;
    float*    cent_sq    = (float*)(ws + o);    o += (size_t)K * 4;
    unsigned* assignment = (unsigned*)(ws + o); o += (size_t)N * 4;
    unsigned* counts     = (unsigned*)(ws + o); o += (size_t)K * 4;
    unsigned* cursor     = (unsigned*)(ws + o); o += (size_t)K * 4;
    unsigned* firstk     = (unsigned*)(ws + o); o += (size_t)D * 4;
    unsigned* canon      = (unsigned*)(ws + o); o += (size_t)K * 4;
    unsigned* keys       = (unsigned*)(ws + o); o += (size_t)N * 4;
    o = (o + 7) & ~(size_t)7;
    unsigned long long* bestg = (unsigned long long*)(ws + o); o += (size_t)N * 8;
    float*    out        = (float*)d_out;

    hipMemsetAsync(counts, 0, (size_t)K * sizeof(unsigned), stream);
    hipMemsetAsync(firstk, 0xFF, (size_t)D * sizeof(unsigned), stream);
    hipMemsetAsync(bestg, 0xFF, (size_t)N * sizeof(unsigned long long), stream);
    hipMemsetAsync(out, 0, (size_t)out_size * sizeof(float), stream);

    canon_first<<<(K + 255) / 256, 256, 0, stream>>>(center_ind, firstk, K);
    canon_map<<<(K + 255) / 256, 256, 0, stream>>>(center_ind, firstk, canon, K);
    gather_centers<<<K, 64, 0, stream>>>(nodes, center_ind, centf, cent_sq, K);
    assign_mfma<<<(N + NT - 1) / NT, 256, 0, stream>>>(nodes, centf, cent_sq, bestg, N, K);
    finalize<<<(N + 255) / 256, 256, 0, stream>>>(bestg, canon, assignment, counts, N);
    scan_offsets<<<1, KK, 0, stream>>>(counts, cursor);
    scatter_idx<<<(N + 255) / 256, 256, 0, stream>>>(assignment, cursor, keys, N);
    aggregate3<<<(N + 4 * CHUNK - 1) / (4 * CHUNK), 256, 0, stream>>>(nodes, keys, out, N);
}

// Round 15
// 561.978 us; speedup vs baseline: 1.0645x; 1.0645x over previous
//
#include <hip/hip_runtime.h>
#include <stdint.h>

// K-means cluster aggregator, round 15: m97-shaped assign GEMM.
// 128 nodes x 128 centers per block, K=512 in 16 steps of 32 dims; 4 waves (2x2),
// each wave 64x64 output = acc[4][4], 16 MFMA + 8 ds_read_b128 per step.
// A (centers) via global_load_lds from fragmented centf; B (nodes) reg-staged
// f32->f16 into [chunk][node] LDS (structural-min bank pattern). 16 KB LDS,
// __launch_bounds__(256,3). Per-(node,center) score chains bit-identical to the
// proven path -> absmax 8.0. Argmin via packed global atomicMin + canon.

typedef _Float16 f16x8  __attribute__((ext_vector_type(8)));
typedef float    f32x4  __attribute__((ext_vector_type(4)));

#define DD 512   // feature dim (fixed)
#define KK 1024  // clusters (fixed)

static __device__ __forceinline__ unsigned orderable(float s) {
    unsigned u = __float_as_uint(s);
    return (u & 0x80000000u) ? ~u : (u | 0x80000000u);
}

static __device__ __forceinline__ void gload_lds16(const void* gsrc, void* ldst) {
    __builtin_amdgcn_global_load_lds(
        (const __attribute__((address_space(1))) unsigned int*)gsrc,
        (__attribute__((address_space(3))) unsigned int*)ldst, 16, 0, 0);
}

// ---- kernel 0a/0b: canonical representative per duplicate-center group ------------
__global__ void canon_first(const int* __restrict__ center_ind,
                            unsigned* __restrict__ firstk, int K) {
    int k = (int)(blockIdx.x * blockDim.x + threadIdx.x);
    if (k < K) atomicMin(&firstk[center_ind[k]], (unsigned)k);
}
__global__ void canon_map(const int* __restrict__ center_ind,
                          const unsigned* __restrict__ firstk,
                          unsigned* __restrict__ canon, int K) {
    int k = (int)(blockIdx.x * blockDim.x + threadIdx.x);
    if (k < K) canon[k] = firstk[center_ind[k]];
}

// ---- kernel 1: gather centers -> 16x16x32 A-fragment layout + fp32 ||c||^2 --------
// Fragment layout (f16): center c -> tile t=c>>4, row r=c&15; 8-dim chunk j:
//   offset = ((t*64 + j)*16 + r) * 8        (per tile: 16 KB; per (t,s): 1 KB block,
//   lane l owns bytes [l*16, l*16+16) — exactly global_load_lds's dst pattern)
__global__ void gather_centers(const float* __restrict__ nodes,
                               const int* __restrict__ center_ind,
                               _Float16* __restrict__ centf,    // [K*DD] fragmented
                               float* __restrict__ cent_sq,     // [K]
                               int K) {
    int k    = (int)blockIdx.x;
    int lane = (int)threadIdx.x;                 // 64 lanes; lane = chunk j
    int ci   = center_ind[k];
    const f32x4* p = reinterpret_cast<const f32x4*>(nodes + (size_t)ci * DD + lane * 8);
    f32x4 v0 = p[0], v1 = p[1];
    f16x8 h;
    h[0]=(_Float16)v0[0]; h[1]=(_Float16)v0[1]; h[2]=(_Float16)v0[2]; h[3]=(_Float16)v0[3];
    h[4]=(_Float16)v1[0]; h[5]=(_Float16)v1[1]; h[6]=(_Float16)v1[2]; h[7]=(_Float16)v1[3];
    int t = k >> 4, r = k & 15;
    *reinterpret_cast<f16x8*>(centf + ((size_t)((t * 64 + lane) * 16 + r) << 3)) = h;
    float ssq = v0[0]*v0[0]+v0[1]*v0[1]+v0[2]*v0[2]+v0[3]*v0[3]
              + v1[0]*v1[0]+v1[1]*v1[1]+v1[2]*v1[2]+v1[3]*v1[3];
    #pragma unroll
    for (int off = 32; off > 0; off >>= 1) ssq += __shfl_xor(ssq, off, 64);
    if (lane == 0) cent_sq[k] = ssq;
}

// ---- kernel 2: MFMA assign (m97-shaped 128x128 GEMM tile) --------------------------
// grid: (nblk = ceil(N/128)) x 8 center-groups, node-group-major.
// wave (w_c,w_n) owns centers [c0+w_c*64,+64) x nodes [n0+w_n*64,+64).
__launch_bounds__(256, 3)
__global__ void assign_mfma(const float* __restrict__ nodes,
                            const _Float16* __restrict__ centf,   // fragmented A
                            const float* __restrict__ cent_sq,    // [K]
                            unsigned long long* __restrict__ bestg, // [N], pre-0xFF
                            int N, int K) {
    __shared__ __align__(16) _Float16 aT[8 * 512];    // 8 KB: A step-tile (frag layout)
    __shared__ __align__(16) _Float16 bT[4 * 1024];   // 8 KB: B step-tile [chunk][node]

    const int tid  = (int)threadIdx.x;
    const int lane = tid & 63;
    const int wid  = tid >> 6;           // 0..3
    const int l15  = lane & 15;
    const int g    = lane >> 4;          // k-slice group / C-row group
    const int nblk = (int)blockIdx.x >> 3;
    const int cblk = (int)blockIdx.x & 7;
    const int n0   = nblk * 128;
    const int c0   = cblk * 128;
    const int w_n  = wid & 1;
    const int w_c  = wid >> 1;

    // B staging ownership: thread -> node nn (0..127), dim-chunk pair j0 (0 or 2)
    const int nn = tid >> 1;
    const int j0 = (tid & 1) * 2;
    const int gn = n0 + nn;
    const bool valid = gn < N;
    const f32x4* bp = reinterpret_cast<const f32x4*>(nodes + (size_t)gn * DD + j0 * 8);

    char* aB = reinterpret_cast<char*>(aT);
    char* bB = reinterpret_cast<char*>(bT);
    const char* cfb = reinterpret_cast<const char*>(centf);
    const size_t asrc0 = (size_t)(c0 >> 4) * 16384;   // center-16-tile base
    const int ta = 2 * wid, tb = 2 * wid + 1;         // this wave's A stage tiles

    f32x4 acc[4][4];                     // [center tile][node group] = 64 regs
    #pragma unroll
    for (int a = 0; a < 4; ++a)
        #pragma unroll
        for (int b = 0; b < 4; ++b) { f32x4 z = {0.f,0.f,0.f,0.f}; acc[a][b] = z; }

    for (int s = 0; s < 16; ++s) {
        // B global loads for this step (issued before the barrier -> latency overlap)
        f32x4 v0 = {0.f,0.f,0.f,0.f}, v1 = v0, v2 = v0, v3 = v0;
        if (valid) { v0 = bp[s*8]; v1 = bp[s*8+1]; v2 = bp[s*8+2]; v3 = bp[s*8+3]; }

        __syncthreads();                 // previous step's LDS reads complete

        f16x8 h0, h1;
        h0[0]=(_Float16)v0[0]; h0[1]=(_Float16)v0[1]; h0[2]=(_Float16)v0[2]; h0[3]=(_Float16)v0[3];
        h0[4]=(_Float16)v1[0]; h0[5]=(_Float16)v1[1]; h0[6]=(_Float16)v1[2]; h0[7]=(_Float16)v1[3];
        h1[0]=(_Float16)v2[0]; h1[1]=(_Float16)v2[1]; h1[2]=(_Float16)v2[2]; h1[3]=(_Float16)v2[3];
        h1[4]=(_Float16)v3[0]; h1[5]=(_Float16)v3[1]; h1[6]=(_Float16)v3[2]; h1[7]=(_Float16)v3[3];
        *reinterpret_cast<f16x8*>(bB + (j0     << 11) + (nn << 4)) = h0;
        *reinterpret_cast<f16x8*>(bB + ((j0+1) << 11) + (nn << 4)) = h1;

        // A stage: 2 contiguous 1 KB gloads per wave (wave-uniform LDS base)
        gload_lds16(cfb + asrc0 + (size_t)ta * 16384 + (size_t)s * 1024 + lane * 16,
                    aB + ta * 1024);
        gload_lds16(cfb + asrc0 + (size_t)tb * 16384 + (size_t)s * 1024 + lane * 16,
                    aB + tb * 1024);

        __syncthreads();                 // staged A (vmcnt) + B (lgkm) visible

        f16x8 Afr[4], Bfr[4];
        #pragma unroll
        for (int tC = 0; tC < 4; ++tC)   // lane-contiguous 1 KB per tile
            Afr[tC] = *reinterpret_cast<const f16x8*>(
                aB + ((w_c * 4 + tC) << 10) + (lane << 4));
        #pragma unroll
        for (int nG = 0; nG < 4; ++nG)   // [chunk g][node] : 16 consecutive 16B/group
            Bfr[nG] = *reinterpret_cast<const f16x8*>(
                bB + (g << 11) + ((w_n * 64 + nG * 16 + l15) << 4));

        __builtin_amdgcn_s_setprio(1);
        #pragma unroll
        for (int tC = 0; tC < 4; ++tC)
            #pragma unroll
            for (int nG = 0; nG < 4; ++nG)
                acc[tC][nG] = __builtin_amdgcn_mfma_f32_16x16x32_f16(
                    Afr[tC], Bfr[nG], acc[tC][nG], 0, 0, 0);
        __builtin_amdgcn_s_setprio(0);
    }

    // epilogue: score = csq - 2*dot; packed min (smallest k on ties).
    // C/D map: col(node) = lane&15, row(center) = g*4 + q  [proven]
    unsigned long long pk[4] = {~0ULL, ~0ULL, ~0ULL, ~0ULL};
    #pragma unroll
    for (int tC = 0; tC < 4; ++tC) {
        const int cb = c0 + w_c * 64 + tC * 16 + g * 4;
        f32x4 cs = *reinterpret_cast<const f32x4*>(cent_sq + cb);
        #pragma unroll
        for (int nG = 0; nG < 4; ++nG) {
            #pragma unroll
            for (int q = 0; q < 4; ++q) {
                float sc = fmaf(-2.f, acc[tC][nG][q], cs[q]);
                unsigned long long v =
                    ((unsigned long long)orderable(sc) << 32) | (unsigned)(cb + q);
                pk[nG] = v < pk[nG] ? v : pk[nG];
            }
        }
    }
    #pragma unroll
    for (int nG = 0; nG < 4; ++nG) {
        unsigned long long p = pk[nG], o;
        o = __shfl_xor(p, 16, 64); p = o < p ? o : p;
        o = __shfl_xor(p, 32, 64); p = o < p ? o : p;
        int n = n0 + w_n * 64 + nG * 16 + l15;
        if (lane < 16 && n < N) atomicMin(&bestg[n], p);
    }
}

// ---- kernel 2b: finalize assignment + histogram from bestg ------------------------
__global__ void finalize(const unsigned long long* __restrict__ bestg,
                         const unsigned* __restrict__ canon,
                         unsigned* __restrict__ assignment,
                         unsigned* __restrict__ counts, int N) {
    int i = (int)(blockIdx.x * blockDim.x + threadIdx.x);
    if (i < N) {
        unsigned k = canon[(unsigned)(bestg[i] & 0xffffffffu)];
        assignment[i] = k;
        atomicAdd(&counts[k], 1u);
    }
}

// ---- kernel 3: exclusive scan of counts -> cursor ---------------------------------
__global__ void scan_offsets(const unsigned* __restrict__ counts,
                             unsigned* __restrict__ cursor) {
    __shared__ unsigned s[KK];
    int t = (int)threadIdx.x;            // 1024
    unsigned c = counts[t];
    s[t] = c;
    __syncthreads();
    for (int off = 1; off < KK; off <<= 1) {
        unsigned v = (t >= off) ? s[t - off] : 0u;
        __syncthreads();
        s[t] += v;
        __syncthreads();
    }
    cursor[t] = s[t] - c;                // exclusive
}

// ---- kernel 4: scatter packed (k<<20 | node) keys into sorted slots ---------------
__global__ void scatter_idx(const unsigned* __restrict__ assignment,
                            unsigned* __restrict__ cursor,
                            unsigned* __restrict__ keys, int N) {
    int i = (int)(blockIdx.x * blockDim.x + threadIdx.x);
    if (i < N) {
        unsigned k = assignment[i];
        unsigned slot = atomicAdd(&cursor[k], 1u);
        keys[slot] = (k << 20) | (unsigned)i;   // N < 2^20, K < 2^10
    }
}

// ---- kernel 5: balanced segmented reduction over sorted slots ---------------------
#define CHUNK 32
__launch_bounds__(256, 4)
__global__ void aggregate3(const float* __restrict__ nodes,
                           const unsigned* __restrict__ keys,   // [N] packed
                           float* __restrict__ out, int N) {
    const int tid  = (int)threadIdx.x;
    const int wid  = tid >> 6;
    const int lane = tid & 63;
    const int base = ((int)blockIdx.x * 4 + wid) * CHUNK;
    if (base >= N) return;
    const int n    = min(CHUNK, N - base);

    int sI = base + (lane & 31);
    unsigned myk = (sI < N) ? keys[sI] : 0u;

    f32x4 a0 = {0.f,0.f,0.f,0.f}, a1 = {0.f,0.f,0.f,0.f};
    int curk = -1;
    auto flush = [&](void) {
        float* dst = out + ((size_t)curk << 9) + lane * 8;
        #pragma unroll
        for (int e = 0; e < 4; ++e) atomicAdd(dst + e, a0[e]);
        #pragma unroll
        for (int e = 0; e < 4; ++e) atomicAdd(dst + 4 + e, a1[e]);
    };

    int j = 0;
    while (j < n) {
        int b = n - j; if (b > 4) b = 4;
        f32x4 r[4][2];
        int   kk[4];
        #pragma unroll
        for (int t = 0; t < 4; ++t) {
            if (t < b) {
                unsigned key = __shfl(myk, j + t, 64);
                kk[t] = (int)(key >> 20);
                const f32x4* p = reinterpret_cast<const f32x4*>(
                    nodes + ((size_t)(key & 0xFFFFFu) << 9) + lane * 8);
                r[t][0] = p[0];
                r[t][1] = p[1];
            }
        }
        #pragma unroll
        for (int t = 0; t < 4; ++t) {
            if (t < b) {
                if (kk[t] != curk) {
                    if (curk >= 0) flush();
                    curk = kk[t];
                    f32x4 z = {0.f,0.f,0.f,0.f}; a0 = z; a1 = z;
                }
                a0 += r[t][0];
                a1 += r[t][1];
            }
        }
        j += 4;
    }
    if (curk >= 0) flush();
}

extern "C" void kernel_launch(void* const* d_in, const int* in_sizes, int n_in,
                              void* d_out, int out_size, void* d_ws, size_t ws_size,
                              hipStream_t stream) {
    const float* nodes      = (const float*)d_in[0];
    const int*   center_ind = (const int*)d_in[1];
    int K = in_sizes[1];                  // 1024
    int D = out_size / K;                 // 512 (DD)
    int N = in_sizes[0] / D;              // 100000

    char* ws = (char*)d_ws;
    _Float16* centf      = (_Float16*)ws;                          // K*DD*2 = 1 MB
    size_t    o          = (size_t)K * DD * 2;
    float*    cent_sq    = (float*)(ws + o);    o += (size_t)K * 4;
    unsigned* assignment = (unsigned*)(ws + o); o += (size_t)N * 4;
    unsigned* counts     = (unsigned*)(ws + o); o += (size_t)K * 4;
    unsigned* cursor     = (unsigned*)(ws + o); o += (size_t)K * 4;
    unsigned* firstk     = (unsigned*)(ws + o); o += (size_t)D * 4;
    unsigned* canon      = (unsigned*)(ws + o); o += (size_t)K * 4;
    unsigned* keys       = (unsigned*)(ws + o); o += (size_t)N * 4;
    o = (o + 7) & ~(size_t)7;
    unsigned long long* bestg = (unsigned long long*)(ws + o); o += (size_t)N * 8;
    float*    out        = (float*)d_out;

    hipMemsetAsync(counts, 0, (size_t)K * sizeof(unsigned), stream);
    hipMemsetAsync(firstk, 0xFF, (size_t)D * sizeof(unsigned), stream);
    hipMemsetAsync(bestg, 0xFF, (size_t)N * sizeof(unsigned long long), stream);
    hipMemsetAsync(out, 0, (size_t)out_size * sizeof(float), stream);

    canon_first<<<(K + 255) / 256, 256, 0, stream>>>(center_ind, firstk, K);
    canon_map<<<(K + 255) / 256, 256, 0, stream>>>(center_ind, firstk, canon, K);
    gather_centers<<<K, 64, 0, stream>>>(nodes, center_ind, centf, cent_sq, K);

    int nblk = (N + 127) / 128;
    assign_mfma<<<nblk * 8, 256, 0, stream>>>(nodes, centf, cent_sq, bestg, N, K);

    finalize<<<(N + 255) / 256, 256, 0, stream>>>(bestg, canon, assignment, counts, N);
    scan_offsets<<<1, KK, 0, stream>>>(counts, cursor);
    scatter_idx<<<(N + 255) / 256, 256, 0, stream>>>(assignment, cursor, keys, N);
    aggregate3<<<(N + 4 * CHUNK - 1) / (4 * CHUNK), 256, 0, stream>>>(nodes, keys, out, N);
}